// Round 7
// baseline (475.655 us; speedup 1.0000x reference)
//
#include <hip/hip_runtime.h>
#include <cstdint>
#include <cstddef>

#define NROWS 4096
#define DO 512
#define DH 1024
#define KNN 10
#define CAND 16

typedef __bf16 bf16;
typedef __bf16 bf16x2_t __attribute__((ext_vector_type(2)));
typedef __bf16 bf16x4_t __attribute__((ext_vector_type(4)));
typedef __bf16 bf16x8 __attribute__((ext_vector_type(8)));
typedef float f32x4 __attribute__((ext_vector_type(4)));
typedef unsigned long long u64;

// ---------- ws layout ----------
constexpr size_t OFF_SQO  = 0;                       // 4096 * 4 = 16384
constexpr size_t OFF_ASUM = 16384;                   // 256 bytes
constexpr size_t OFF_MASK = 16640;                   // 4096 * 128 * 4 = 2097152
constexpr size_t OFF_SIM  = 2113792;                 // 4096 * 1024 * 2 = 8388608
// per-tile candidates (8 MB) live in out1 (free until cos GEMM);
// bf16 original (4 MB) lives in out0 until cos GEMM.

__device__ __forceinline__ void gld_lds16(const void* g, void* l) {
  __builtin_amdgcn_global_load_lds(
      (const __attribute__((address_space(1))) unsigned int*)g,
      (__attribute__((address_space(3))) unsigned int*)l, 16, 0, 0);
}

__device__ __forceinline__ unsigned wave_min_u32(unsigned v) {
#pragma unroll
  for (int m = 32; m > 0; m >>= 1) {
    unsigned o = __shfl_xor(v, m);
    v = o < v ? o : v;
  }
  return v;
}

__device__ __forceinline__ u64 wave_min_u64(u64 v) {
#pragma unroll
  for (int m = 32; m > 0; m >>= 1) {
    unsigned lo = __shfl_xor((unsigned)v, m);
    unsigned hi = __shfl_xor((unsigned)(v >> 32), m);
    u64 o = ((u64)hi << 32) | lo;
    v = o < v ? o : v;
  }
  return v;
}

// ---------- K0: fused prep — sqo + bf16(original) | normalized bf16(hidden) | zero mask/a_sum ----------
__global__ __launch_bounds__(256) void prep_k(const float* __restrict__ orig,
                                              const float* __restrict__ hid,
                                              float* __restrict__ sqo,
                                              bf16* __restrict__ abf,
                                              bf16* __restrict__ sim,
                                              unsigned int* __restrict__ mask,
                                              int* __restrict__ a_sum) {
  int b = blockIdx.x;
  int tid = threadIdx.x;
  __shared__ float red[256];
  if (b < NROWS) {
    float2 v = ((const float2*)(orig + (size_t)b * DO))[tid];
    bf16x2_t o; o[0] = (bf16)v.x; o[1] = (bf16)v.y;
    ((bf16x2_t*)(abf + (size_t)b * DO))[tid] = o;
    red[tid] = v.x * v.x + v.y * v.y;
    __syncthreads();
    for (int off = 128; off > 0; off >>= 1) {
      if (tid < off) red[tid] += red[tid + off];
      __syncthreads();
    }
    if (tid == 0) sqo[b] = red[0];
  } else if (b < 2 * NROWS) {
    int r = b - NROWS;
    float4 v = ((const float4*)(hid + (size_t)r * DH))[tid];
    red[tid] = v.x * v.x + v.y * v.y + v.z * v.z + v.w * v.w;
    __syncthreads();
    for (int off = 128; off > 0; off >>= 1) {
      if (tid < off) red[tid] += red[tid + off];
      __syncthreads();
    }
    float scale = 1.0f / fmaxf(sqrtf(red[0]), 1e-12f);
    bf16x4_t o;
    o[0] = (bf16)(v.x * scale);
    o[1] = (bf16)(v.y * scale);
    o[2] = (bf16)(v.z * scale);
    o[3] = (bf16)(v.w * scale);
    ((bf16x4_t*)(sim + (size_t)r * DH))[tid] = o;
  } else {
    int zb = b - 2 * NROWS;                    // 0..128: zero 2 MB mask + a_sum
    if (zb < 128) {
      uint4* dst = (uint4*)mask;
      uint4 z = uint4{0u, 0u, 0u, 0u};
#pragma unroll
      for (int k = 0; k < 4; ++k) dst[(size_t)zb * 1024 + k * 256 + tid] = z;
    } else if (tid == 0) {
      *a_sum = 0;
    }
  }
}

// ---------- K1: bf16 MFMA GEMM (BK=64, swizzled LDS) + in-tile per-row top-16 epilogue ----------
// MFMA core identical to R6 (proven). Epilogue: no D2 write; instead stage the
// 128x128 d2 tile to LDS in 64-row halves and select each row's top-16 keys
// (key = (f32bits & 0xFFFFF000) | global_col, same quantization as R6's topk),
// writing cand_t[row][tile][16].
union D2Smem {
  struct { bf16 A[128 * 64]; bf16 B[128 * 64]; } g;   // 32 KB staging
  float tile[64 * 128];                               // 32 KB epilogue d2 half-tile
  unsigned mrg[64 * 65];                              // 16.6 KB merge overlay
};

__global__ __launch_bounds__(256) void d2approx_k(const bf16* __restrict__ Ab,
                                                  const float* __restrict__ sqo,
                                                  unsigned* __restrict__ cand_t) {
  __shared__ D2Smem sm;
  int id = blockIdx.x;
  int swz = (id & 7) * 128 + (id >> 3);        // XCD-aware swizzle (1024 % 8 == 0)
  int bi = swz >> 5, bj = swz & 31;
  int row0 = bi * 128, col0 = bj * 128;
  int tid = threadIdx.x, wave = tid >> 6, lane = tid & 63;
  int wr = wave >> 1, wc = wave & 1;
  int lr = lane & 15, lk = lane >> 4;
  int sw = lr & 7;                             // frag-read swizzle (row&7 == lr&7)

  f32x4 acc[4][4];
#pragma unroll
  for (int m = 0; m < 4; ++m)
#pragma unroll
    for (int n = 0; n < 4; ++n) acc[m][n] = f32x4{0.f, 0.f, 0.f, 0.f};

  for (int kt = 0; kt < DO; kt += 64) {
#pragma unroll
    for (int s = 0; s < 4; ++s) {
      int c = s * 256 + tid;                   // linear 16B chunk, 1024 per matrix
      int r = c >> 3;
      int g = (c & 7) ^ (r & 7);               // pre-swizzled global group
      bf16* baseA = sm.g.A + (size_t)(s * 256 + wave * 64) * 8;  // wave-uniform dest
      bf16* baseB = sm.g.B + (size_t)(s * 256 + wave * 64) * 8;
      gld_lds16(Ab + (size_t)(row0 + r) * DO + kt + g * 8, baseA);
      gld_lds16(Ab + (size_t)(col0 + r) * DO + kt + g * 8, baseB);
    }
    __syncthreads();
#pragma unroll
    for (int kb = 0; kb < 2; ++kb) {
      bf16x8 af[4], bfr[4];
#pragma unroll
      for (int m = 0; m < 4; ++m) {
        int ra = wr * 64 + m * 16 + lr;
        int rb = wc * 64 + m * 16 + lr;
        int slot = (kb * 4 + lk) ^ sw;
        af[m]  = *(const bf16x8*)&sm.g.A[ra * 64 + slot * 8];
        bfr[m] = *(const bf16x8*)&sm.g.B[rb * 64 + slot * 8];
      }
#pragma unroll
      for (int m = 0; m < 4; ++m)
#pragma unroll
        for (int n = 0; n < 4; ++n)
          acc[m][n] = __builtin_amdgcn_mfma_f32_16x16x32_bf16(af[m], bfr[n],
                                                              acc[m][n], 0, 0, 0);
    }
    __syncthreads();
  }

  float sqc[4];
#pragma unroll
  for (int n = 0; n < 4; ++n) sqc[n] = sqo[col0 + wc * 64 + n * 16 + lr];

  int er = tid & 63, eq = tid >> 6;            // epilogue row / 32-col chunk
#pragma unroll
  for (int cc = 0; cc < 2; ++cc) {
    __syncthreads();                           // tile buffer free
    if (wr == cc) {
#pragma unroll
      for (int m = 0; m < 4; ++m)
#pragma unroll
        for (int g = 0; g < 4; ++g) {
          int rl = m * 16 + lk * 4 + g;        // 0..63 within half
          float sr = sqo[row0 + cc * 64 + rl];
#pragma unroll
          for (int n = 0; n < 4; ++n) {
            float d = fmaxf(sr + sqc[n] - 2.0f * acc[m][n][g], 0.0f);
            sm.tile[rl * 128 + wc * 64 + n * 16 + lr] = d;
          }
        }
    }
    __syncthreads();
    // pass 1: 4 threads/row, 32 cols each; row-rotated reads (conflict-free)
    unsigned lst[CAND];
#pragma unroll
    for (int t = 0; t < CAND; ++t) lst[t] = 0xFFFFFFFFu;
#pragma unroll
    for (int k = 0; k < 32; ++k) {
      int s = (k + er) & 31;
      float v = sm.tile[er * 128 + eq * 32 + s];
      unsigned key = (__float_as_uint(v) & 0xFFFFF000u) | (unsigned)(col0 + eq * 32 + s);
      if (key < lst[CAND - 1]) {
        lst[CAND - 1] = key;
#pragma unroll
        for (int t = CAND - 1; t > 0; --t) {
          if (lst[t] < lst[t - 1]) { unsigned tmp = lst[t]; lst[t] = lst[t - 1]; lst[t - 1] = tmp; }
        }
      }
    }
    __syncthreads();                           // tile reads done; overlay mrg
#pragma unroll
    for (int i = 0; i < CAND; ++i) sm.mrg[er * 65 + eq * 16 + i] = lst[i];
    __syncthreads();
    if (tid < 64) {                            // merge 64 -> top-16 per row
      unsigned fl[CAND];
#pragma unroll
      for (int t = 0; t < CAND; ++t) fl[t] = 0xFFFFFFFFu;
      for (int k = 0; k < 64; ++k) {
        unsigned key = sm.mrg[tid * 65 + k];
        if (key < fl[CAND - 1]) {
          fl[CAND - 1] = key;
#pragma unroll
          for (int t = CAND - 1; t > 0; --t) {
            if (fl[t] < fl[t - 1]) { unsigned tmp = fl[t]; fl[t] = fl[t - 1]; fl[t - 1] = tmp; }
          }
        }
      }
      unsigned* dst = cand_t + (size_t)(row0 + cc * 64 + tid) * 512 + bj * 16;
#pragma unroll
      for (int i = 0; i < CAND; ++i) dst[i] = fl[i];
    }
  }
}

// ---------- K2: merge candidates -> exact fp64 rescore -> top-10 -> mask + a_sum ----------
__global__ __launch_bounds__(256) void rescore_mask_k(const float* __restrict__ A,
                                                      const float* __restrict__ sqo,
                                                      const unsigned* __restrict__ cand_t,
                                                      unsigned int* __restrict__ mask,
                                                      int* __restrict__ a_sum) {
  int row = blockIdx.x;
  int tid = threadIdx.x;
  int wave = tid >> 6, lane = tid & 63;
  __shared__ float xi[DO];
  __shared__ int cnd[CAND];
  __shared__ u64 rkeys[CAND];
  ((float2*)xi)[tid] = ((const float2*)(A + (size_t)row * DO))[tid];

  if (wave == 0) {                             // merge 512 tile-keys -> global top-16
    const unsigned* p = cand_t + (size_t)row * 512;
    unsigned lst[CAND];
#pragma unroll
    for (int t = 0; t < CAND; ++t) lst[t] = 0xFFFFFFFFu;
    uint4 v0 = ((const uint4*)p)[lane * 2];
    uint4 v1 = ((const uint4*)p)[lane * 2 + 1];
    unsigned kv[8] = {v0.x, v0.y, v0.z, v0.w, v1.x, v1.y, v1.z, v1.w};
#pragma unroll
    for (int i = 0; i < 8; ++i) {
      unsigned key = kv[i];
      if (key < lst[CAND - 1]) {
        lst[CAND - 1] = key;
#pragma unroll
        for (int t = CAND - 1; t > 0; --t) {
          if (lst[t] < lst[t - 1]) { unsigned tmp = lst[t]; lst[t] = lst[t - 1]; lst[t - 1] = tmp; }
        }
      }
    }
    for (int s = 0; s < CAND; ++s) {
      unsigned w = wave_min_u32(lst[0]);
      if (lst[0] == w) {                       // keys unique -> exactly one lane pops
#pragma unroll
        for (int t = 0; t < CAND - 1; ++t) lst[t] = lst[t + 1];
        lst[CAND - 1] = 0xFFFFFFFFu;
      }
      if (lane == 0) cnd[s] = (int)(w & 0xFFFu);
    }
  }
  __syncthreads();

  int g = lane >> 4;                           // 4 cands per wave
  int c = cnd[wave * 4 + g];
  int seg = lane & 15;                         // 32 dims per lane
  const float* xc = A + (size_t)c * DO + seg * 32;
  const float* xr = xi + seg * 32;
  double dot = 0.0;
#pragma unroll
  for (int q = 0; q < 8; ++q) {
    int qq = (q + seg) & 7;                    // rotate to spread LDS banks
    float4 a = *(const float4*)(xr + qq * 4);
    float4 b = *(const float4*)(xc + qq * 4);
    dot = fma((double)a.x, (double)b.x, dot);
    dot = fma((double)a.y, (double)b.y, dot);
    dot = fma((double)a.z, (double)b.z, dot);
    dot = fma((double)a.w, (double)b.w, dot);
  }
#pragma unroll
  for (int m2 = 1; m2 < 16; m2 <<= 1) dot += __shfl_xor(dot, m2);
  if (seg == 0) {
    double d2 = (double)sqo[row] + (double)sqo[c] - 2.0 * dot;
    float d2f = (float)fmax(d2, 0.0);
    rkeys[wave * 4 + g] = ((u64)__float_as_uint(d2f) << 32) | (unsigned)c;
  }
  __syncthreads();

  // final top-10 -> symmetric mask bits + a_sum via 0->1 transition counting
  if (wave == 0) {
    u64 v = (lane < CAND) ? rkeys[lane] : ~0ULL;
    int newcnt = 0;
    int rw = row >> 5;
    unsigned rbit = 1u << (row & 31);
    for (int s = 0; s < KNN; ++s) {
      u64 w = wave_min_u64(v);
      if (v == w) v = ~0ULL;
      if (lane == 0) {
        int j = (int)(w & 0xFFFFFFFFULL);
        unsigned jbit = 1u << (j & 31);
        unsigned old1 = atomicOr(mask + (size_t)row * (NROWS / 32) + (j >> 5), jbit);
        if (!(old1 & jbit)) ++newcnt;
        unsigned old2 = atomicOr(mask + (size_t)j * (NROWS / 32) + rw, rbit);
        if (!(old2 & rbit)) ++newcnt;
      }
    }
    if (lane == 0 && newcnt) atomicAdd(a_sum, newcnt);
  }
}

// ---------- K3: bf16 MFMA cosine GEMM (BK=64, swizzled) + fused finalize epilogue ----------
__global__ __launch_bounds__(256) void gemm_cos_fused_k(const bf16* __restrict__ S,
                                                        const unsigned int* __restrict__ mask,
                                                        const int* __restrict__ a_sum_p,
                                                        float* __restrict__ out0,
                                                        float* __restrict__ out1) {
  __shared__ bf16 Asm[128 * 64];
  __shared__ bf16 Bsm[128 * 64];
  int id = blockIdx.x;
  int swz = (id & 7) * 128 + (id >> 3);
  int bi = swz >> 5, bj = swz & 31;
  int row0 = bi * 128, col0 = bj * 128;
  int tid = threadIdx.x, wave = tid >> 6, lane = tid & 63;
  int wr = wave >> 1, wc = wave & 1;
  int lr = lane & 15, lk = lane >> 4;
  int sw = lr & 7;

  f32x4 acc[4][4];
#pragma unroll
  for (int m = 0; m < 4; ++m)
#pragma unroll
    for (int n = 0; n < 4; ++n) acc[m][n] = f32x4{0.f, 0.f, 0.f, 0.f};

  for (int kt = 0; kt < DH; kt += 64) {
#pragma unroll
    for (int s = 0; s < 4; ++s) {
      int c = s * 256 + tid;
      int r = c >> 3;
      int g = (c & 7) ^ (r & 7);
      bf16* baseA = Asm + (size_t)(s * 256 + wave * 64) * 8;
      bf16* baseB = Bsm + (size_t)(s * 256 + wave * 64) * 8;
      gld_lds16(S + (size_t)(row0 + r) * DH + kt + g * 8, baseA);
      gld_lds16(S + (size_t)(col0 + r) * DH + kt + g * 8, baseB);
    }
    __syncthreads();
#pragma unroll
    for (int kb = 0; kb < 2; ++kb) {
      bf16x8 af[4], bfr[4];
#pragma unroll
      for (int m = 0; m < 4; ++m) {
        int ra = wr * 64 + m * 16 + lr;
        int rb = wc * 64 + m * 16 + lr;
        int slot = (kb * 4 + lk) ^ sw;
        af[m]  = *(const bf16x8*)&Asm[ra * 64 + slot * 8];
        bfr[m] = *(const bf16x8*)&Bsm[rb * 64 + slot * 8];
      }
#pragma unroll
      for (int m = 0; m < 4; ++m)
#pragma unroll
        for (int n = 0; n < 4; ++n)
          acc[m][n] = __builtin_amdgcn_mfma_f32_16x16x32_bf16(af[m], bfr[n],
                                                              acc[m][n], 0, 0, 0);
    }
    __syncthreads();
  }

  // stage this tile's mask slice (128 rows x 4 words) into LDS (reuse Asm)
  unsigned* lmask = (unsigned*)Asm;
  {
    int w0 = tid;
    lmask[w0] = mask[(size_t)(row0 + (w0 >> 2)) * 128 + bj * 4 + (w0 & 3)];
    int w1 = tid + 256;
    lmask[w1] = mask[(size_t)(row0 + (w1 >> 2)) * 128 + bj * 4 + (w1 & 3)];
  }
  __syncthreads();

  float asum = (float)(*a_sum_p);
  float Nw = 0.5f / asum;                      // (1-ALPHA)/a_sum
  float Nb = 1.0f / (16777216.0f - 2.0f * asum);

#pragma unroll
  for (int m = 0; m < 4; ++m) {
#pragma unroll
    for (int g = 0; g < 4; ++g) {
      int rl = wr * 64 + m * 16 + lk * 4 + g;
      size_t rowoff = (size_t)(row0 + rl) * NROWS;
#pragma unroll
      for (int n = 0; n < 4; ++n) {
        int cl = wc * 64 + n * 16 + lr;
        unsigned wbit = lmask[rl * 4 + (cl >> 5)];
        unsigned a = (wbit >> (cl & 31)) & 1u;
        float cv = acc[m][n][g];
        out0[rowoff + col0 + cl] = a ? 0.0f : Nb * cv;
        out1[rowoff + col0 + cl] = a ? Nw * cv : 0.0f;
      }
    }
  }
}

extern "C" void kernel_launch(void* const* d_in, const int* in_sizes, int n_in,
                              void* d_out, int out_size, void* d_ws, size_t ws_size,
                              hipStream_t stream) {
  const float* original = (const float*)d_in[0];
  const float* hidden   = (const float*)d_in[1];
  float* out0 = (float*)d_out;                       // non_anchor_out
  float* out1 = out0 + (size_t)NROWS * NROWS;        // anchor_out
  bf16*     Ab     = (bf16*)out0;                    // bf16 original scratch (4 MB)
  unsigned* cand_t = (unsigned*)out1;                // per-tile candidates (8 MB)

  char* ws = (char*)d_ws;
  float*        sqo   = (float*)(ws + OFF_SQO);
  int*          a_sum = (int*)(ws + OFF_ASUM);
  unsigned int* mask  = (unsigned int*)(ws + OFF_MASK);
  bf16*         sim   = (bf16*)(ws + OFF_SIM);

  prep_k<<<2 * NROWS + 129, 256, 0, stream>>>(original, hidden, sqo, Ab, sim, mask, a_sum);
  d2approx_k<<<1024, 256, 0, stream>>>(Ab, sqo, cand_t);
  rescore_mask_k<<<NROWS, 256, 0, stream>>>(original, sqo, cand_t, mask, a_sum);
  gemm_cos_fused_k<<<1024, 256, 0, stream>>>(sim, mask, a_sum, out0, out1);
}